// Round 1
// baseline (1228.100 us; speedup 1.0000x reference)
//
#include <hip/hip_runtime.h>
#include <math.h>

// Problem dims (fixed): B=2, S=2048 -> TOK=4096 tokens; H=4096; I=11008
#define TOK 4096
#define HD  4096
#define ID  11008

typedef int i32x4 __attribute__((ext_vector_type(4)));
typedef float f32x4v __attribute__((ext_vector_type(4)));
typedef char i8x4v __attribute__((ext_vector_type(4)));

#define GLDS16(g, l) __builtin_amdgcn_global_load_lds( \
    (const __attribute__((address_space(1))) void*)(g), \
    (__attribute__((address_space(3))) void*)(l), 16, 0, 0)

// ---------------------------------------------------------------- convert ---
// All four f32 -> i8 converts fused into one launch. Reads are streamed-once
// (765MB) -> non-temporal so they don't thrash L3 ahead of the GEMMs; writes
// (191MB i8 total) stay cacheable -> L3-resident for the GEMMs that read them.
__global__ void conv_all(const float* __restrict__ x,  char* __restrict__ xq,
                         const float* __restrict__ wg, char* __restrict__ wgq,
                         const float* __restrict__ wu, char* __restrict__ wuq,
                         const float* __restrict__ wd, char* __restrict__ wdq)
{
  const long NX = (long)TOK * HD / 4, NW = (long)ID * HD / 4;
  const long total = NX + 3 * NW;
  const long stride = (long)gridDim.x * blockDim.x;
  for (long i = (long)blockIdx.x * blockDim.x + threadIdx.x; i < total;
       i += stride) {
    const f32x4v* src; i8x4v* dst; long j;
    if (i < NX)               { src = (const f32x4v*)x;  dst = (i8x4v*)xq;  j = i; }
    else if (i < NX + NW)     { src = (const f32x4v*)wg; dst = (i8x4v*)wgq; j = i - NX; }
    else if (i < NX + 2 * NW) { src = (const f32x4v*)wu; dst = (i8x4v*)wuq; j = i - NX - NW; }
    else                      { src = (const f32x4v*)wd; dst = (i8x4v*)wdq; j = i - NX - 2 * NW; }
    f32x4v v = __builtin_nontemporal_load(&src[j]);
    i8x4v o;
    o.x = (char)(int)rintf(v.x);
    o.y = (char)(int)rintf(v.y);
    o.z = (char)(int)rintf(v.z);
    o.w = (char)(int)rintf(v.w);
    dst[j] = o;
  }
}

// ----------------------------------------------------------------- GEMM -----
// out[m,n] = sum_k A[m,k]*B[n,k]  (both K-major int8), i32 accumulate (exact).
//
// R8: 256x256 tile, BK=64, 8 waves (2Mx4N, 128x64 per wave), 4-deep LDS
// pipeline (4 bufs x (A 16KB + B 16KB) = 128KB), 2 phases per K-tile:
//   { ds_read subtile | stage half of tile t+3 ; barrier ; lgkmcnt(0) ;
//     setprio(1) ; 16 MFMA ; setprio(0) ; barrier }
// Counted vmcnt at iteration end, placed BEFORE the closing barrier so every
// wave's own stage loads for tile t+1 have landed before any wave reads them:
//   steady state vmcnt(8) (2 tiles x 4 loads/thread in flight), epilogue
//   drains 8 -> 4 -> 0.  Never vmcnt(0) in the main loop (T3+T4), setprio
//   around MFMA clusters (T5).
//
// LDS swizzle: within each 64B row, 16B chunk c stored at slot c^(row&3).
// Both the GLDS16 linear writes (pre-swizzled per-lane global source) and the
// ds_read_b128 fragment reads then spread uniformly over all 32 banks.
//
// MODE 0: gate -> ga = silu(acc*gs), store f32, sum|ga| -> sums[0]
// MODE 1: up   -> inter = clip(rint(ga/ga_s))*acc*(ga_s*up_s), store f32,
//                 sum|inter| -> sums[1]
// MODE 2: down -> plain f32 store (exact integers)
template<int MODE>
__global__ __launch_bounds__(512, 2)
void gemm_i8(const char* __restrict__ A,
             const char* __restrict__ Bm,
             int M, int N, int K,
             float* __restrict__ Cout,
             const float* __restrict__ ga_in,
             const float* __restrict__ sc0,
             const float* __restrict__ sc1,
             double* __restrict__ sums,
             long long NN)
{
  __shared__ __align__(16) char Ls[131072];   // [4][16KB] A, then [4][16KB] B

  const int tid  = threadIdx.x;
  const int wv   = tid >> 6;        // wave 0..7
  const int lane = tid & 63;
  const int wr   = lane & 15;
  const int qd   = lane >> 4;

  // wave tile: 2 (M) x 4 (N); per-wave output 128x64
  const int WM = (wv >> 2) << 7;    // 0 or 128
  const int WN = (wv & 3) << 6;     // 0,64,128,192

  // XCD-aware swizzle (bijection: grid = 8 * (2 * n_tiles))
  const int L   = blockIdx.x;
  const int xcd = L & 7;
  const int p   = L >> 3;
  const int m0  = (xcd + ((p & 1) << 3)) << 8;   // m_tile 0..15
  const int n0  = (p >> 1) << 8;                 // n_tile 0..N/256-1

  // staging geometry: per K-tile each thread does 2 A-GLDS16 + 2 B-GLDS16.
  // linear chunk u = wv*128 + q*64 + lane ; row = u>>2 ; slot = u&3 holds
  // global chunk c = slot ^ (row&3).
  const int srow   = (wv << 5) + (lane >> 2);          // + q*16
  const int schunk = (lane & 3) ^ ((lane >> 2) & 3);
  const char* gA = A  + (size_t)(m0 + srow) * K + (schunk << 4);
  const char* gB = Bm + (size_t)(n0 + srow) * K + (schunk << 4);
  const size_t r16K = (size_t)16 * K;
  char* sA = Ls + (wv << 11);            // + buf*16384, issues at +0 / +1024
  char* sB = Ls + 65536 + (wv << 11);

  // fragment ds_read offsets: lane reads row (frag_row*16 + wr), chunk qd,
  // at slot qd^(row&3) = qd^(wr&3).
  const int rsw  = (qd ^ (wr & 3)) << 4;
  const int aoff = ((WM + wr) << 6) + rsw;
  const int boff = ((WN + wr) << 6) + rsw;

  i32x4 acc[8][4] = {};
  const int NT = K >> 6;

#define STAGE_A(t) do { const char* g_ = gA + (size_t)((t) << 6);          \
    char* l_ = sA + (((t) & 3) << 14);                                     \
    GLDS16(g_, l_); GLDS16(g_ + r16K, l_ + 1024); } while (0)
#define STAGE_B(t) do { const char* g_ = gB + (size_t)((t) << 6);          \
    char* l_ = sB + (((t) & 3) << 14);                                     \
    GLDS16(g_, l_); GLDS16(g_ + r16K, l_ + 1024); } while (0)

  // prologue: stage tiles 0,1,2 (12 loads); wait until only 8 newest remain
  // -> tile 0 landed; barrier publishes it to all waves.
  STAGE_A(0); STAGE_B(0);
  STAGE_A(1); STAGE_B(1);
  STAGE_A(2); STAGE_B(2);
  asm volatile("s_waitcnt vmcnt(8)" ::: "memory");
  __builtin_amdgcn_s_barrier();

#pragma unroll 4
  for (int t = 0; t < NT; ++t) {
    const char* bufA = Ls + ((t & 3) << 14);
    const char* bufB = Ls + 65536 + ((t & 3) << 14);

    // ---- phase A: frag rows 0-3 (+ all B frags), stage A of tile t+3 ----
    i32x4 af[4], bf[4];
#pragma unroll
    for (int i = 0; i < 4; i++)
      af[i] = *(const i32x4*)(bufA + aoff + (i << 10));
#pragma unroll
    for (int j = 0; j < 4; j++)
      bf[j] = *(const i32x4*)(bufB + boff + (j << 10));
    if (t + 3 < NT) STAGE_A(t + 3);
    __builtin_amdgcn_s_barrier();
    asm volatile("s_waitcnt lgkmcnt(0)" ::: "memory");
    __builtin_amdgcn_s_setprio(1);
#pragma unroll
    for (int i = 0; i < 4; i++)
#pragma unroll
      for (int j = 0; j < 4; j++)
        acc[i][j] = __builtin_amdgcn_mfma_i32_16x16x64_i8(af[i], bf[j],
                                                          acc[i][j], 0, 0, 0);
    __builtin_amdgcn_s_setprio(0);
    __builtin_amdgcn_s_barrier();

    // ---- phase B: frag rows 4-7, stage B of tile t+3 ----
    i32x4 a2[4];
#pragma unroll
    for (int i = 0; i < 4; i++)
      a2[i] = *(const i32x4*)(bufA + aoff + ((i + 4) << 10));
    if (t + 3 < NT) STAGE_B(t + 3);
    __builtin_amdgcn_s_barrier();
    asm volatile("s_waitcnt lgkmcnt(0)" ::: "memory");
    __builtin_amdgcn_s_setprio(1);
#pragma unroll
    for (int i = 0; i < 4; i++)
#pragma unroll
      for (int j = 0; j < 4; j++)
        acc[i + 4][j] = __builtin_amdgcn_mfma_i32_16x16x64_i8(a2[i], bf[j],
                                                              acc[i + 4][j],
                                                              0, 0, 0);
    __builtin_amdgcn_s_setprio(0);
    // gate for next iter's reads of tile t+1; before the barrier so every
    // wave's own loads are landed before any wave crosses.
    if (t + 3 < NT)      asm volatile("s_waitcnt vmcnt(8)" ::: "memory");
    else if (t + 2 < NT) asm volatile("s_waitcnt vmcnt(4)" ::: "memory");
    else if (t + 1 < NT) asm volatile("s_waitcnt vmcnt(0)" ::: "memory");
    __builtin_amdgcn_s_barrier();
  }
#undef STAGE_A
#undef STAGE_B

  // epilogue: C/D layout col = lane&15 (n), row = quad*4 + reg (m)
  double lsum = 0.0;

  if (MODE == 0) {
    const float gs = sc0[0] * sc1[0];
#pragma unroll
    for (int i = 0; i < 8; i++) {
      const int mb = m0 + WM + (i << 4) + (qd << 2);
#pragma unroll
      for (int j = 0; j < 4; j++) {
        const int n = n0 + WN + (j << 4) + wr;
#pragma unroll
        for (int r2 = 0; r2 < 4; r2++) {
          float g = (float)acc[i][j][r2] * gs;
          float s = g / (1.0f + expf(-g));          // silu
          __builtin_nontemporal_store(s, &Cout[(size_t)(mb + r2) * N + n]);
          lsum += (double)fabsf(s);
        }
      }
    }
  } else if (MODE == 1) {
    const float up_s  = sc0[0] * sc1[0];
    const float ga_s  = (float)(sums[0] / (double)NN) + 1e-8f;
    const float combo = ga_s * up_s;
#pragma unroll
    for (int i = 0; i < 8; i++) {
      const int mb = m0 + WM + (i << 4) + (qd << 2);
#pragma unroll
      for (int j = 0; j < 4; j++) {
        const int n = n0 + WN + (j << 4) + wr;
#pragma unroll
        for (int r2 = 0; r2 < 4; r2++) {
          float up = (float)acc[i][j][r2];
          float ga = __builtin_nontemporal_load(
                         &ga_in[(size_t)(mb + r2) * N + n]);
          float gq = fmaxf(-128.0f, fminf(127.0f, rintf(ga / ga_s)));
          float itv = gq * up * combo;              // same assoc as reference
          __builtin_nontemporal_store(itv, &Cout[(size_t)(mb + r2) * N + n]);
          lsum += (double)fabsf(itv);
        }
      }
    }
  } else {
#pragma unroll
    for (int i = 0; i < 8; i++) {
      const int mb = m0 + WM + (i << 4) + (qd << 2);
#pragma unroll
      for (int j = 0; j < 4; j++) {
        const int n = n0 + WN + (j << 4) + wr;
#pragma unroll
        for (int r2 = 0; r2 < 4; r2++)
          __builtin_nontemporal_store((float)acc[i][j][r2],
                                      &Cout[(size_t)(mb + r2) * N + n]);
      }
    }
  }

  if (MODE != 2) {
    for (int off = 32; off; off >>= 1) lsum += __shfl_down(lsum, off, 64);
    double* red = (double*)Ls;        // safe: all LDS reads done at loop exit
    if (lane == 0) red[wv] = lsum;
    __syncthreads();
    if (tid == 0) {
      double s2 = 0.0;
#pragma unroll
      for (int k2 = 0; k2 < 8; k2++) s2 += red[k2];
      atomicAdd(&sums[MODE], s2);
    }
  }
}

// ------------------------------------------------------------- quantize -----
__global__ void quant_inter(const float* __restrict__ inter,
                            char* __restrict__ outq,
                            const double* __restrict__ sums, long long NN,
                            const float* __restrict__ wsd,
                            float* __restrict__ scalar_out, int n4)
{
  const float is = (float)(sums[1] / (double)NN) + 1e-8f;
  if (blockIdx.x == 0 && threadIdx.x == 0) scalar_out[0] = is * wsd[0];
  int stride = gridDim.x * blockDim.x;
  for (int i = blockIdx.x * blockDim.x + threadIdx.x; i < n4; i += stride) {
    f32x4v v = __builtin_nontemporal_load(&((const f32x4v*)inter)[i]);
    i8x4v o;
    o.x = (char)(int)fmaxf(-128.0f, fminf(127.0f, rintf(v.x / is)));
    o.y = (char)(int)fmaxf(-128.0f, fminf(127.0f, rintf(v.y / is)));
    o.z = (char)(int)fmaxf(-128.0f, fminf(127.0f, rintf(v.z / is)));
    o.w = (char)(int)fmaxf(-128.0f, fminf(127.0f, rintf(v.w / is)));
    ((i8x4v*)outq)[i] = o;                 // cacheable: GEMM2 reads it next
  }
}

// ---------------------------------------------------------------- launch ----
extern "C" void kernel_launch(void* const* d_in, const int* in_sizes, int n_in,
                              void* d_out, int out_size, void* d_ws, size_t ws_size,
                              hipStream_t stream) {
  const float* x        = (const float*)d_in[0];
  const float* x_scale  = (const float*)d_in[1];
  const float* qw_gate  = (const float*)d_in[2];
  const float* ws_gate  = (const float*)d_in[3];
  const float* qw_up    = (const float*)d_in[4];
  const float* ws_up    = (const float*)d_in[5];
  const float* qw_down  = (const float*)d_in[6];
  const float* ws_down  = (const float*)d_in[7];
  float* out = (float*)d_out;

  char* ws = (char*)d_ws;
  double* sums = (double*)ws;                 // [0]=sum|ga| [1]=sum|inter|
  size_t off = 256;
  char* xq     = ws + off; off += (size_t)TOK * HD;
  char* wgq    = ws + off; off += (size_t)ID * HD;
  char* wuq    = ws + off; off += (size_t)ID * HD;
  char* wdq    = ws + off; off += (size_t)HD * ID;
  char* interq = ws + off; off += (size_t)TOK * ID;
  float* ga    = (float*)(ws + off); off += (size_t)TOK * ID * 4;
  float* inter = (float*)(ws + off); off += (size_t)TOK * ID * 4;

  const long long NN = (long long)TOK * ID;

  (void)hipMemsetAsync(sums, 0, 16, stream);

  // all four converts in one launch
  conv_all<<<8192, 256, 0, stream>>>(x, xq, qw_gate, wgq, qw_up, wuq,
                                     qw_down, wdq);

  // gate GEMM + silu + sum|ga|   (grid = (ID/256)*(TOK/256) = 43*16 = 688)
  gemm_i8<0><<<dim3((ID / 256) * (TOK / 256)), 512, 0, stream>>>(
      xq, wgq, TOK, ID, HD, ga, nullptr, x_scale, ws_gate, sums, NN);

  // up GEMM + inter computation + sum|inter|
  gemm_i8<1><<<dim3((ID / 256) * (TOK / 256)), 512, 0, stream>>>(
      xq, wuq, TOK, ID, HD, inter, ga, x_scale, ws_up, sums, NN);

  // quantize inter -> int8; also write scalar output
  quant_inter<<<8192, 256, 0, stream>>>(inter, interq, sums, NN, ws_down,
                                        out + (size_t)TOK * HD, (int)(NN / 4));

  // down GEMM -> final output (grid = (HD/256)*(TOK/256) = 16*16 = 256)
  gemm_i8<2><<<dim3((HD / 256) * (TOK / 256)), 512, 0, stream>>>(
      interq, wdq, TOK, HD, ID, out, nullptr, nullptr, nullptr, sums, NN);
}

// Round 2
// 1180.099 us; speedup vs baseline: 1.0407x; 1.0407x over previous
//
#include <hip/hip_runtime.h>
#include <math.h>

// Problem dims (fixed): B=2, S=2048 -> TOK=4096 tokens; H=4096; I=11008
#define TOK 4096
#define HD  4096
#define ID  11008

typedef int i32x4 __attribute__((ext_vector_type(4)));
typedef float f32x4v __attribute__((ext_vector_type(4)));
typedef char i8x4v __attribute__((ext_vector_type(4)));

#define GLDS16(g, l) __builtin_amdgcn_global_load_lds( \
    (const __attribute__((address_space(1))) void*)(g), \
    (__attribute__((address_space(3))) void*)(l), 16, 0, 0)

// ---------------------------------------------------------------- convert ---
__global__ void conv_all(const float* __restrict__ x,  char* __restrict__ xq,
                         const float* __restrict__ wg, char* __restrict__ wgq,
                         const float* __restrict__ wu, char* __restrict__ wuq,
                         const float* __restrict__ wd, char* __restrict__ wdq)
{
  const long NX = (long)TOK * HD / 4, NW = (long)ID * HD / 4;
  const long total = NX + 3 * NW;
  const long stride = (long)gridDim.x * blockDim.x;
  for (long i = (long)blockIdx.x * blockDim.x + threadIdx.x; i < total;
       i += stride) {
    const f32x4v* src; i8x4v* dst; long j;
    if (i < NX)               { src = (const f32x4v*)x;  dst = (i8x4v*)xq;  j = i; }
    else if (i < NX + NW)     { src = (const f32x4v*)wg; dst = (i8x4v*)wgq; j = i - NX; }
    else if (i < NX + 2 * NW) { src = (const f32x4v*)wu; dst = (i8x4v*)wuq; j = i - NX - NW; }
    else                      { src = (const f32x4v*)wd; dst = (i8x4v*)wdq; j = i - NX - 2 * NW; }
    f32x4v v = __builtin_nontemporal_load(&src[j]);
    i8x4v o;
    o.x = (char)(int)rintf(v.x);
    o.y = (char)(int)rintf(v.y);
    o.z = (char)(int)rintf(v.z);
    o.w = (char)(int)rintf(v.w);
    dst[j] = o;
  }
}

// ----------------------------------------------------------------- GEMM -----
// out[m,n] = sum_k A[m,k]*B[n,k]  (both K-major int8), i32 accumulate (exact).
//
// R9: same 256x256 / BK=64 / 8-wave / 4-deep pipeline as R8, but with the
// bank swizzle FIXED.  Bank-group of a 16B chunk = (4*row + slot) & 7; the
// 4*row term only contributes 4*(row&1), so the XOR bits must come from row
// bits [2:1], NOT [1:0] (R8's row&3 swizzle left only 4 distinct bank-groups
// -> 4-way conflict on every ds_read_b128 -> 1.69e7 SQ_LDS_BANK_CONFLICT).
//   store: slot(c,row) = c ^ ((row>>1)&3)
//   read : chunk c of row at slot c ^ ((row>>1)&3)
// Verified by hand: every consecutive 8 lanes of a fragment ds_read_b128 hit
// all 8 bank-groups, for both qd halves, A and B.  Write side stays linear
// (GLDS16 requirement); the same involution is applied to the per-lane
// GLOBAL source chunk instead: schunk = (lane&3) ^ ((lane>>3)&3).
//
// Pipeline (unchanged from R8): 2 phases per K-tile:
//   { ds_read subtile | stage half of tile t+3 ; barrier ; lgkmcnt(0) ;
//     setprio(1) ; 16 MFMA ; setprio(0) ; barrier }
// with counted vmcnt(8) at iteration end (never 0 in main loop), epilogue
// drains 8 -> 4 -> 0.
//
// MODE 0: gate -> ga = silu(acc*gs), store f32, sum|ga| -> sums[0]
// MODE 1: up   -> inter = clip(rint(ga/ga_s))*acc*(ga_s*up_s), store f32,
//                 sum|inter| -> sums[1]
// MODE 2: down -> plain f32 store (exact integers)
template<int MODE>
__global__ __launch_bounds__(512, 2)
void gemm_i8(const char* __restrict__ A,
             const char* __restrict__ Bm,
             int M, int N, int K,
             float* __restrict__ Cout,
             const float* __restrict__ ga_in,
             const float* __restrict__ sc0,
             const float* __restrict__ sc1,
             double* __restrict__ sums,
             long long NN)
{
  __shared__ __align__(16) char Ls[131072];   // [4][16KB] A, then [4][16KB] B

  const int tid  = threadIdx.x;
  const int wv   = tid >> 6;        // wave 0..7
  const int lane = tid & 63;
  const int wr   = lane & 15;
  const int qd   = lane >> 4;

  // wave tile: 2 (M) x 4 (N); per-wave output 128x64
  const int WM = (wv >> 2) << 7;    // 0 or 128
  const int WN = (wv & 3) << 6;     // 0,64,128,192

  // XCD-aware swizzle (bijection: grid = 8 * (2 * n_tiles))
  const int L   = blockIdx.x;
  const int xcd = L & 7;
  const int p   = L >> 3;
  const int m0  = (xcd + ((p & 1) << 3)) << 8;   // m_tile 0..15
  const int n0  = (p >> 1) << 8;                 // n_tile 0..N/256-1

  // staging geometry: per K-tile each thread does 2 A-GLDS16 + 2 B-GLDS16.
  // physical slot u = wv*128 + q*64 + lane ; row = u>>2 ; slot = u&3 holds
  // global chunk c = slot ^ ((row>>1)&3)  ->  schunk = (lane&3)^((lane>>3)&3)
  const int srow   = (wv << 5) + (lane >> 2);          // + q*16
  const int schunk = (lane & 3) ^ ((lane >> 3) & 3);
  const char* gA = A  + (size_t)(m0 + srow) * K + (schunk << 4);
  const char* gB = Bm + (size_t)(n0 + srow) * K + (schunk << 4);
  const size_t r16K = (size_t)16 * K;
  char* sA = Ls + (wv << 11);            // + buf*16384, issues at +0 / +1024
  char* sB = Ls + 65536 + (wv << 11);

  // fragment ds_read offsets: lane reads row (frag_row*16 + wr), chunk qd,
  // at slot qd ^ ((row>>1)&3) = qd ^ ((wr>>1)&3)   (frag_row*16 contributes 0)
  const int rsw  = (qd ^ ((wr >> 1) & 3)) << 4;
  const int aoff = ((WM + wr) << 6) + rsw;
  const int boff = ((WN + wr) << 6) + rsw;

  i32x4 acc[8][4] = {};
  const int NT = K >> 6;

#define STAGE_A(t) do { const char* g_ = gA + (size_t)((t) << 6);          \
    char* l_ = sA + (((t) & 3) << 14);                                     \
    GLDS16(g_, l_); GLDS16(g_ + r16K, l_ + 1024); } while (0)
#define STAGE_B(t) do { const char* g_ = gB + (size_t)((t) << 6);          \
    char* l_ = sB + (((t) & 3) << 14);                                     \
    GLDS16(g_, l_); GLDS16(g_ + r16K, l_ + 1024); } while (0)

  // prologue: stage tiles 0,1,2 (12 loads); wait until only 8 newest remain
  // -> tile 0 landed; barrier publishes it to all waves.
  STAGE_A(0); STAGE_B(0);
  STAGE_A(1); STAGE_B(1);
  STAGE_A(2); STAGE_B(2);
  asm volatile("s_waitcnt vmcnt(8)" ::: "memory");
  __builtin_amdgcn_s_barrier();

#pragma unroll 4
  for (int t = 0; t < NT; ++t) {
    const char* bufA = Ls + ((t & 3) << 14);
    const char* bufB = Ls + 65536 + ((t & 3) << 14);

    // ---- phase A: frag rows 0-3 (+ all B frags), stage A of tile t+3 ----
    i32x4 af[4], bf[4];
#pragma unroll
    for (int i = 0; i < 4; i++)
      af[i] = *(const i32x4*)(bufA + aoff + (i << 10));
#pragma unroll
    for (int j = 0; j < 4; j++)
      bf[j] = *(const i32x4*)(bufB + boff + (j << 10));
    if (t + 3 < NT) STAGE_A(t + 3);
    __builtin_amdgcn_s_barrier();
    asm volatile("s_waitcnt lgkmcnt(0)" ::: "memory");
    __builtin_amdgcn_s_setprio(1);
#pragma unroll
    for (int i = 0; i < 4; i++)
#pragma unroll
      for (int j = 0; j < 4; j++)
        acc[i][j] = __builtin_amdgcn_mfma_i32_16x16x64_i8(af[i], bf[j],
                                                          acc[i][j], 0, 0, 0);
    __builtin_amdgcn_s_setprio(0);
    __builtin_amdgcn_s_barrier();

    // ---- phase B: frag rows 4-7, stage B of tile t+3 ----
    i32x4 a2[4];
#pragma unroll
    for (int i = 0; i < 4; i++)
      a2[i] = *(const i32x4*)(bufA + aoff + ((i + 4) << 10));
    if (t + 3 < NT) STAGE_B(t + 3);
    __builtin_amdgcn_s_barrier();
    asm volatile("s_waitcnt lgkmcnt(0)" ::: "memory");
    __builtin_amdgcn_s_setprio(1);
#pragma unroll
    for (int i = 0; i < 4; i++)
#pragma unroll
      for (int j = 0; j < 4; j++)
        acc[i + 4][j] = __builtin_amdgcn_mfma_i32_16x16x64_i8(a2[i], bf[j],
                                                              acc[i + 4][j],
                                                              0, 0, 0);
    __builtin_amdgcn_s_setprio(0);
    // gate for next iter's reads of tile t+1; before the barrier so every
    // wave's own loads are landed before any wave crosses.
    if (t + 3 < NT)      asm volatile("s_waitcnt vmcnt(8)" ::: "memory");
    else if (t + 2 < NT) asm volatile("s_waitcnt vmcnt(4)" ::: "memory");
    else if (t + 1 < NT) asm volatile("s_waitcnt vmcnt(0)" ::: "memory");
    __builtin_amdgcn_s_barrier();
  }
#undef STAGE_A
#undef STAGE_B

  // epilogue: C/D layout col = lane&15 (n), row = quad*4 + reg (m)
  double lsum = 0.0;

  if (MODE == 0) {
    const float gs = sc0[0] * sc1[0];
#pragma unroll
    for (int i = 0; i < 8; i++) {
      const int mb = m0 + WM + (i << 4) + (qd << 2);
#pragma unroll
      for (int j = 0; j < 4; j++) {
        const int n = n0 + WN + (j << 4) + wr;
#pragma unroll
        for (int r2 = 0; r2 < 4; r2++) {
          float g = (float)acc[i][j][r2] * gs;
          float s = g / (1.0f + expf(-g));          // silu
          __builtin_nontemporal_store(s, &Cout[(size_t)(mb + r2) * N + n]);
          lsum += (double)fabsf(s);
        }
      }
    }
  } else if (MODE == 1) {
    const float up_s  = sc0[0] * sc1[0];
    const float ga_s  = (float)(sums[0] / (double)NN) + 1e-8f;
    const float combo = ga_s * up_s;
#pragma unroll
    for (int i = 0; i < 8; i++) {
      const int mb = m0 + WM + (i << 4) + (qd << 2);
#pragma unroll
      for (int j = 0; j < 4; j++) {
        const int n = n0 + WN + (j << 4) + wr;
#pragma unroll
        for (int r2 = 0; r2 < 4; r2++) {
          float up = (float)acc[i][j][r2];
          float ga = __builtin_nontemporal_load(
                         &ga_in[(size_t)(mb + r2) * N + n]);
          float gq = fmaxf(-128.0f, fminf(127.0f, rintf(ga / ga_s)));
          float itv = gq * up * combo;              // same assoc as reference
          __builtin_nontemporal_store(itv, &Cout[(size_t)(mb + r2) * N + n]);
          lsum += (double)fabsf(itv);
        }
      }
    }
  } else {
#pragma unroll
    for (int i = 0; i < 8; i++) {
      const int mb = m0 + WM + (i << 4) + (qd << 2);
#pragma unroll
      for (int j = 0; j < 4; j++) {
        const int n = n0 + WN + (j << 4) + wr;
#pragma unroll
        for (int r2 = 0; r2 < 4; r2++)
          __builtin_nontemporal_store((float)acc[i][j][r2],
                                      &Cout[(size_t)(mb + r2) * N + n]);
      }
    }
  }

  if (MODE != 2) {
    for (int off = 32; off; off >>= 1) lsum += __shfl_down(lsum, off, 64);
    double* red = (double*)Ls;        // safe: all LDS reads done at loop exit
    if (lane == 0) red[wv] = lsum;
    __syncthreads();
    if (tid == 0) {
      double s2 = 0.0;
#pragma unroll
      for (int k2 = 0; k2 < 8; k2++) s2 += red[k2];
      atomicAdd(&sums[MODE], s2);
    }
  }
}

// ------------------------------------------------------------- quantize -----
__global__ void quant_inter(const float* __restrict__ inter,
                            char* __restrict__ outq,
                            const double* __restrict__ sums, long long NN,
                            const float* __restrict__ wsd,
                            float* __restrict__ scalar_out, int n4)
{
  const float is = (float)(sums[1] / (double)NN) + 1e-8f;
  if (blockIdx.x == 0 && threadIdx.x == 0) scalar_out[0] = is * wsd[0];
  int stride = gridDim.x * blockDim.x;
  for (int i = blockIdx.x * blockDim.x + threadIdx.x; i < n4; i += stride) {
    f32x4v v = __builtin_nontemporal_load(&((const f32x4v*)inter)[i]);
    i8x4v o;
    o.x = (char)(int)fmaxf(-128.0f, fminf(127.0f, rintf(v.x / is)));
    o.y = (char)(int)fmaxf(-128.0f, fminf(127.0f, rintf(v.y / is)));
    o.z = (char)(int)fmaxf(-128.0f, fminf(127.0f, rintf(v.z / is)));
    o.w = (char)(int)fmaxf(-128.0f, fminf(127.0f, rintf(v.w / is)));
    ((i8x4v*)outq)[i] = o;                 // cacheable: GEMM2 reads it next
  }
}

// ---------------------------------------------------------------- launch ----
extern "C" void kernel_launch(void* const* d_in, const int* in_sizes, int n_in,
                              void* d_out, int out_size, void* d_ws, size_t ws_size,
                              hipStream_t stream) {
  const float* x        = (const float*)d_in[0];
  const float* x_scale  = (const float*)d_in[1];
  const float* qw_gate  = (const float*)d_in[2];
  const float* ws_gate  = (const float*)d_in[3];
  const float* qw_up    = (const float*)d_in[4];
  const float* ws_up    = (const float*)d_in[5];
  const float* qw_down  = (const float*)d_in[6];
  const float* ws_down  = (const float*)d_in[7];
  float* out = (float*)d_out;

  char* ws = (char*)d_ws;
  double* sums = (double*)ws;                 // [0]=sum|ga| [1]=sum|inter|
  size_t off = 256;
  char* xq     = ws + off; off += (size_t)TOK * HD;
  char* wgq    = ws + off; off += (size_t)ID * HD;
  char* wuq    = ws + off; off += (size_t)ID * HD;
  char* wdq    = ws + off; off += (size_t)HD * ID;
  char* interq = ws + off; off += (size_t)TOK * ID;
  float* ga    = (float*)(ws + off); off += (size_t)TOK * ID * 4;
  float* inter = (float*)(ws + off); off += (size_t)TOK * ID * 4;

  const long long NN = (long long)TOK * ID;

  (void)hipMemsetAsync(sums, 0, 16, stream);

  // all four converts in one launch
  conv_all<<<8192, 256, 0, stream>>>(x, xq, qw_gate, wgq, qw_up, wuq,
                                     qw_down, wdq);

  // gate GEMM + silu + sum|ga|   (grid = (ID/256)*(TOK/256) = 43*16 = 688)
  gemm_i8<0><<<dim3((ID / 256) * (TOK / 256)), 512, 0, stream>>>(
      xq, wgq, TOK, ID, HD, ga, nullptr, x_scale, ws_gate, sums, NN);

  // up GEMM + inter computation + sum|inter|
  gemm_i8<1><<<dim3((ID / 256) * (TOK / 256)), 512, 0, stream>>>(
      xq, wuq, TOK, ID, HD, inter, ga, x_scale, ws_up, sums, NN);

  // quantize inter -> int8; also write scalar output
  quant_inter<<<8192, 256, 0, stream>>>(inter, interq, sums, NN, ws_down,
                                        out + (size_t)TOK * HD, (int)(NN / 4));

  // down GEMM -> final output (grid = (HD/256)*(TOK/256) = 16*16 = 256)
  gemm_i8<2><<<dim3((HD / 256) * (TOK / 256)), 512, 0, stream>>>(
      interq, wdq, TOK, HD, ID, out, nullptr, nullptr, nullptr, sums, NN);
}

// Round 3
// 1126.939 us; speedup vs baseline: 1.0898x; 1.0472x over previous
//
#include <hip/hip_runtime.h>
#include <math.h>

// Problem dims (fixed): B=2, S=2048 -> TOK=4096 tokens; H=4096; I=11008
#define TOK 4096
#define HD  4096
#define ID  11008

typedef int i32x4 __attribute__((ext_vector_type(4)));
typedef float f32x4v __attribute__((ext_vector_type(4)));
typedef char i8x4v __attribute__((ext_vector_type(4)));

#define GLDS16(g, l) __builtin_amdgcn_global_load_lds( \
    (const __attribute__((address_space(1))) void*)(g), \
    (__attribute__((address_space(3))) void*)(l), 16, 0, 0)

// ---------------------------------------------------------------- convert ---
__global__ void conv_all(const float* __restrict__ x,  char* __restrict__ xq,
                         const float* __restrict__ wg, char* __restrict__ wgq,
                         const float* __restrict__ wu, char* __restrict__ wuq,
                         const float* __restrict__ wd, char* __restrict__ wdq)
{
  const long NX = (long)TOK * HD / 4, NW = (long)ID * HD / 4;
  const long total = NX + 3 * NW;
  const long stride = (long)gridDim.x * blockDim.x;
  for (long i = (long)blockIdx.x * blockDim.x + threadIdx.x; i < total;
       i += stride) {
    const f32x4v* src; i8x4v* dst; long j;
    if (i < NX)               { src = (const f32x4v*)x;  dst = (i8x4v*)xq;  j = i; }
    else if (i < NX + NW)     { src = (const f32x4v*)wg; dst = (i8x4v*)wgq; j = i - NX; }
    else if (i < NX + 2 * NW) { src = (const f32x4v*)wu; dst = (i8x4v*)wuq; j = i - NX - NW; }
    else                      { src = (const f32x4v*)wd; dst = (i8x4v*)wdq; j = i - NX - 2 * NW; }
    f32x4v v = __builtin_nontemporal_load(&src[j]);
    i8x4v o;
    o.x = (char)(int)rintf(v.x);
    o.y = (char)(int)rintf(v.y);
    o.z = (char)(int)rintf(v.z);
    o.w = (char)(int)rintf(v.w);
    dst[j] = o;
  }
}

// ----------------------------------------------------------------- GEMM -----
// out[m,n] = sum_k A[m,k]*B[n,k]  (both K-major int8), i32 accumulate (exact).
//
// R10: same 256x256 / BK=64 / 8-wave / 4-buf geometry + R9's verified bank
// swizzle, but the schedule is rebuilt to kill the serial chain R9 exposed
// (4 lockstep barriers/K-tile, reads never overlapping MFMA -> 26% MfmaUtil):
//   * ds_reads issued one HALF-PHASE ahead, so they drain under the MFMA
//     cluster (per-wave overlap, barrier-independent).
//   * ONE barrier per K-tile (was 4).  Buffer-overwrite safety: each wave's
//     lgkmcnt(0) precedes the barrier, so at crossing, all reads of buf t are
//     complete; stages of t+2 are issued only after it.
//   * counted vmcnt(2) mid-loop (steady queue = [A(t+1)2,B(t+1)2,A(t+2)2]);
//     drains 0 only in the last two iterations.
// Per K-tile per wave: A-half { issue a2 reads | STAGE_A(t+2) ; lgkm(4) ;
// 16 MFMA rows0-3 }, B-half { vmcnt(2) ; lgkm(0) ; barrier ; issue af/bf
// reads of t+1 | STAGE_B(t+2) ; 16 MFMA rows4-7 }.
//
// LDS swizzle (R9, verified 0 conflicts): 16B chunk c of row r stored at
// slot c ^ ((r>>1)&3); GLDS writes stay linear via pre-swizzled global
// source chunk schunk = (lane&3)^((lane>>3)&3).
//
// MODE 0: gate -> ga = silu(acc*gs), store f32, sum|ga| -> sums[0]
// MODE 1: up   -> inter = clip(rint(ga/ga_s))*acc*(ga_s*up_s), store f32,
//                 sum|inter| -> sums[1]
// MODE 2: down -> plain f32 store (exact integers)
template<int MODE>
__global__ __launch_bounds__(512, 2)
void gemm_i8(const char* __restrict__ A,
             const char* __restrict__ Bm,
             int M, int N, int K,
             float* __restrict__ Cout,
             const float* __restrict__ ga_in,
             const float* __restrict__ sc0,
             const float* __restrict__ sc1,
             double* __restrict__ sums,
             long long NN)
{
  __shared__ __align__(16) char Ls[131072];   // [4][16KB] A, then [4][16KB] B

  const int tid  = threadIdx.x;
  const int wv   = tid >> 6;        // wave 0..7
  const int lane = tid & 63;
  const int wr   = lane & 15;
  const int qd   = lane >> 4;

  // wave tile: 2 (M) x 4 (N); per-wave output 128x64
  const int WM = (wv >> 2) << 7;    // 0 or 128
  const int WN = (wv & 3) << 6;     // 0,64,128,192

  // XCD-aware swizzle (bijection: grid = 8 * (2 * n_tiles))
  const int L   = blockIdx.x;
  const int xcd = L & 7;
  const int p   = L >> 3;
  const int m0  = (xcd + ((p & 1) << 3)) << 8;   // m_tile 0..15
  const int n0  = (p >> 1) << 8;                 // n_tile 0..N/256-1

  // staging: per K-tile each thread does 2 A-GLDS16 + 2 B-GLDS16.
  const int srow   = (wv << 5) + (lane >> 2);          // + q*16
  const int schunk = (lane & 3) ^ ((lane >> 3) & 3);
  const char* gA = A  + (size_t)(m0 + srow) * K + (schunk << 4);
  const char* gB = Bm + (size_t)(n0 + srow) * K + (schunk << 4);
  const size_t r16K = (size_t)16 * K;
  char* sA = Ls + (wv << 11);            // + buf*16384, issues at +0 / +1024
  char* sB = Ls + 65536 + (wv << 11);

  // fragment ds_read offsets: lane reads row (frag_row*16 + wr), chunk qd,
  // at slot qd ^ ((wr>>1)&3)
  const int rsw  = (qd ^ ((wr >> 1) & 3)) << 4;
  const int aoff = ((WM + wr) << 6) + rsw;
  const int boff = ((WN + wr) << 6) + rsw;

  i32x4 acc[8][4] = {};
  const int NT = K >> 6;

#define STAGE_A(t) do { const char* g_ = gA + (size_t)((t) << 6);          \
    char* l_ = sA + (((t) & 3) << 14);                                     \
    GLDS16(g_, l_); GLDS16(g_ + r16K, l_ + 1024); } while (0)
#define STAGE_B(t) do { const char* g_ = gB + (size_t)((t) << 6);          \
    char* l_ = sB + (((t) & 3) << 14);                                     \
    GLDS16(g_, l_); GLDS16(g_ + r16K, l_ + 1024); } while (0)

  // prologue: stage tiles 0 and 1 (8 loads); vmcnt(4) -> tile 0 landed;
  // barrier publishes; then issue tile-0 af/bf reads (consumed in iter 0).
  STAGE_A(0); STAGE_B(0);
  STAGE_A(1); STAGE_B(1);
  asm volatile("s_waitcnt vmcnt(4)" ::: "memory");
  __builtin_amdgcn_s_barrier();

  i32x4 af[4], bf[4], afn[4], bfn[4], a2[4];
  {
    const char* bufA0 = Ls;
    const char* bufB0 = Ls + 65536;
#pragma unroll
    for (int i = 0; i < 4; i++)
      af[i] = *(const i32x4*)(bufA0 + aoff + (i << 10));
#pragma unroll
    for (int j = 0; j < 4; j++)
      bf[j] = *(const i32x4*)(bufB0 + boff + (j << 10));
  }

#pragma unroll 4
  for (int t = 0; t < NT; ++t) {
    const char* bufA = Ls + ((t & 3) << 14);

    // ---- A-half: issue rows4-7 reads | stage A(t+2); MFMA rows0-3 ----
#pragma unroll
    for (int i = 0; i < 4; i++)
      a2[i] = *(const i32x4*)(bufA + aoff + ((i + 4) << 10));
    if (t + 2 < NT) STAGE_A(t + 2);
    asm volatile("s_waitcnt lgkmcnt(4)" ::: "memory");  // af/bf(t) ready
    __builtin_amdgcn_s_setprio(1);
#pragma unroll
    for (int i = 0; i < 4; i++)
#pragma unroll
      for (int j = 0; j < 4; j++)
        acc[i][j] = __builtin_amdgcn_mfma_i32_16x16x64_i8(af[i], bf[j],
                                                          acc[i][j], 0, 0, 0);
    __builtin_amdgcn_s_setprio(0);

    // ---- B-half: gate t+1; one barrier; issue t+1 reads | stage B(t+2);
    //      MFMA rows4-7 overlaps the t+1 reads ----
    if (t + 2 < NT)      asm volatile("s_waitcnt vmcnt(2)" ::: "memory");
    else if (t + 1 < NT) asm volatile("s_waitcnt vmcnt(0)" ::: "memory");
    asm volatile("s_waitcnt lgkmcnt(0)" ::: "memory");  // my buf-t reads done
    if (t + 1 < NT) {
      __builtin_amdgcn_s_barrier();
      const char* nA = Ls + (((t + 1) & 3) << 14);
      const char* nB = Ls + 65536 + (((t + 1) & 3) << 14);
#pragma unroll
      for (int i = 0; i < 4; i++)
        afn[i] = *(const i32x4*)(nA + aoff + (i << 10));
#pragma unroll
      for (int j = 0; j < 4; j++)
        bfn[j] = *(const i32x4*)(nB + boff + (j << 10));
      if (t + 2 < NT) STAGE_B(t + 2);
    }
    __builtin_amdgcn_s_setprio(1);
#pragma unroll
    for (int i = 0; i < 4; i++)
#pragma unroll
      for (int j = 0; j < 4; j++)
        acc[i + 4][j] = __builtin_amdgcn_mfma_i32_16x16x64_i8(a2[i], bf[j],
                                                              acc[i + 4][j],
                                                              0, 0, 0);
    __builtin_amdgcn_s_setprio(0);
#pragma unroll
    for (int i = 0; i < 4; i++) { af[i] = afn[i]; bf[i] = bfn[i]; }
  }
#undef STAGE_A
#undef STAGE_B

  // epilogue: C/D layout col = lane&15 (n), row = quad*4 + reg (m)
  double lsum = 0.0;

  if (MODE == 0) {
    const float gs = sc0[0] * sc1[0];
#pragma unroll
    for (int i = 0; i < 8; i++) {
      const int mb = m0 + WM + (i << 4) + (qd << 2);
#pragma unroll
      for (int j = 0; j < 4; j++) {
        const int n = n0 + WN + (j << 4) + wr;
#pragma unroll
        for (int r2 = 0; r2 < 4; r2++) {
          float g = (float)acc[i][j][r2] * gs;
          float s = g / (1.0f + expf(-g));          // silu
          __builtin_nontemporal_store(s, &Cout[(size_t)(mb + r2) * N + n]);
          lsum += (double)fabsf(s);
        }
      }
    }
  } else if (MODE == 1) {
    const float up_s  = sc0[0] * sc1[0];
    const float ga_s  = (float)(sums[0] / (double)NN) + 1e-8f;
    const float combo = ga_s * up_s;
#pragma unroll
    for (int i = 0; i < 8; i++) {
      const int mb = m0 + WM + (i << 4) + (qd << 2);
#pragma unroll
      for (int j = 0; j < 4; j++) {
        const int n = n0 + WN + (j << 4) + wr;
#pragma unroll
        for (int r2 = 0; r2 < 4; r2++) {
          float up = (float)acc[i][j][r2];
          float ga = __builtin_nontemporal_load(
                         &ga_in[(size_t)(mb + r2) * N + n]);
          float gq = fmaxf(-128.0f, fminf(127.0f, rintf(ga / ga_s)));
          float itv = gq * up * combo;              // same assoc as reference
          __builtin_nontemporal_store(itv, &Cout[(size_t)(mb + r2) * N + n]);
          lsum += (double)fabsf(itv);
        }
      }
    }
  } else {
#pragma unroll
    for (int i = 0; i < 8; i++) {
      const int mb = m0 + WM + (i << 4) + (qd << 2);
#pragma unroll
      for (int j = 0; j < 4; j++) {
        const int n = n0 + WN + (j << 4) + wr;
#pragma unroll
        for (int r2 = 0; r2 < 4; r2++)
          __builtin_nontemporal_store((float)acc[i][j][r2],
                                      &Cout[(size_t)(mb + r2) * N + n]);
      }
    }
  }

  if (MODE != 2) {
    for (int off = 32; off; off >>= 1) lsum += __shfl_down(lsum, off, 64);
    double* red = (double*)Ls;        // safe: all LDS reads done at loop exit
    if (lane == 0) red[wv] = lsum;
    __syncthreads();
    if (tid == 0) {
      double s2 = 0.0;
#pragma unroll
      for (int k2 = 0; k2 < 8; k2++) s2 += red[k2];
      atomicAdd(&sums[MODE], s2);
    }
  }
}

// ------------------------------------------------------------- quantize -----
__global__ void quant_inter(const float* __restrict__ inter,
                            char* __restrict__ outq,
                            const double* __restrict__ sums, long long NN,
                            const float* __restrict__ wsd,
                            float* __restrict__ scalar_out, int n4)
{
  const float is = (float)(sums[1] / (double)NN) + 1e-8f;
  if (blockIdx.x == 0 && threadIdx.x == 0) scalar_out[0] = is * wsd[0];
  int stride = gridDim.x * blockDim.x;
  for (int i = blockIdx.x * blockDim.x + threadIdx.x; i < n4; i += stride) {
    f32x4v v = __builtin_nontemporal_load(&((const f32x4v*)inter)[i]);
    i8x4v o;
    o.x = (char)(int)fmaxf(-128.0f, fminf(127.0f, rintf(v.x / is)));
    o.y = (char)(int)fmaxf(-128.0f, fminf(127.0f, rintf(v.y / is)));
    o.z = (char)(int)fmaxf(-128.0f, fminf(127.0f, rintf(v.z / is)));
    o.w = (char)(int)fmaxf(-128.0f, fminf(127.0f, rintf(v.w / is)));
    ((i8x4v*)outq)[i] = o;                 // cacheable: GEMM2 reads it next
  }
}

// ---------------------------------------------------------------- launch ----
extern "C" void kernel_launch(void* const* d_in, const int* in_sizes, int n_in,
                              void* d_out, int out_size, void* d_ws, size_t ws_size,
                              hipStream_t stream) {
  const float* x        = (const float*)d_in[0];
  const float* x_scale  = (const float*)d_in[1];
  const float* qw_gate  = (const float*)d_in[2];
  const float* ws_gate  = (const float*)d_in[3];
  const float* qw_up    = (const float*)d_in[4];
  const float* ws_up    = (const float*)d_in[5];
  const float* qw_down  = (const float*)d_in[6];
  const float* ws_down  = (const float*)d_in[7];
  float* out = (float*)d_out;

  char* ws = (char*)d_ws;
  double* sums = (double*)ws;                 // [0]=sum|ga| [1]=sum|inter|
  size_t off = 256;
  char* xq     = ws + off; off += (size_t)TOK * HD;
  char* wgq    = ws + off; off += (size_t)ID * HD;
  char* wuq    = ws + off; off += (size_t)ID * HD;
  char* wdq    = ws + off; off += (size_t)HD * ID;
  char* interq = ws + off; off += (size_t)TOK * ID;
  float* ga    = (float*)(ws + off); off += (size_t)TOK * ID * 4;
  float* inter = (float*)(ws + off); off += (size_t)TOK * ID * 4;

  const long long NN = (long long)TOK * ID;

  (void)hipMemsetAsync(sums, 0, 16, stream);

  // all four converts in one launch
  conv_all<<<8192, 256, 0, stream>>>(x, xq, qw_gate, wgq, qw_up, wuq,
                                     qw_down, wdq);

  // gate GEMM + silu + sum|ga|   (grid = (ID/256)*(TOK/256) = 43*16 = 688)
  gemm_i8<0><<<dim3((ID / 256) * (TOK / 256)), 512, 0, stream>>>(
      xq, wgq, TOK, ID, HD, ga, nullptr, x_scale, ws_gate, sums, NN);

  // up GEMM + inter computation + sum|inter|
  gemm_i8<1><<<dim3((ID / 256) * (TOK / 256)), 512, 0, stream>>>(
      xq, wuq, TOK, ID, HD, inter, ga, x_scale, ws_up, sums, NN);

  // quantize inter -> int8; also write scalar output
  quant_inter<<<8192, 256, 0, stream>>>(inter, interq, sums, NN, ws_down,
                                        out + (size_t)TOK * HD, (int)(NN / 4));

  // down GEMM -> final output (grid = (HD/256)*(TOK/256) = 16*16 = 256)
  gemm_i8<2><<<dim3((HD / 256) * (TOK / 256)), 512, 0, stream>>>(
      interq, wdq, TOK, HD, ID, out, nullptr, nullptr, nullptr, sums, NN);
}

// Round 4
// 1123.254 us; speedup vs baseline: 1.0933x; 1.0033x over previous
//
#include <hip/hip_runtime.h>
#include <math.h>

// Problem dims (fixed): B=2, S=2048 -> TOK=4096 tokens; H=4096; I=11008
#define TOK 4096
#define HD  4096
#define ID  11008

typedef int i32x4 __attribute__((ext_vector_type(4)));
typedef float f32x4v __attribute__((ext_vector_type(4)));  // ext-vector: OK for nontemporal builtins
typedef char i8x4v __attribute__((ext_vector_type(4)));

#define GLDS16(g, l) __builtin_amdgcn_global_load_lds( \
    (const __attribute__((address_space(1))) void*)(g), \
    (__attribute__((address_space(3))) void*)(l), 16, 0, 0)

// ---------------------------------------------------------------- convert ---
// All four f32 -> i8 converts fused into one launch. Reads are streamed-once
// (765MB) -> non-temporal so they don't thrash L3 ahead of the GEMMs; writes
// (191MB i8 total) stay cacheable -> L3-resident for the GEMMs that read them.
__global__ void conv_all(const float* __restrict__ x,  char* __restrict__ xq,
                         const float* __restrict__ wg, char* __restrict__ wgq,
                         const float* __restrict__ wu, char* __restrict__ wuq,
                         const float* __restrict__ wd, char* __restrict__ wdq)
{
  const long NX = (long)TOK * HD / 4, NW = (long)ID * HD / 4;
  const long total = NX + 3 * NW;
  const long stride = (long)gridDim.x * blockDim.x;
  for (long i = (long)blockIdx.x * blockDim.x + threadIdx.x; i < total;
       i += stride) {
    const f32x4v* src; i8x4v* dst; long j;
    if (i < NX)               { src = (const f32x4v*)x;  dst = (i8x4v*)xq;  j = i; }
    else if (i < NX + NW)     { src = (const f32x4v*)wg; dst = (i8x4v*)wgq; j = i - NX; }
    else if (i < NX + 2 * NW) { src = (const f32x4v*)wu; dst = (i8x4v*)wuq; j = i - NX - NW; }
    else                      { src = (const f32x4v*)wd; dst = (i8x4v*)wdq; j = i - NX - 2 * NW; }
    f32x4v v = __builtin_nontemporal_load(&src[j]);
    i8x4v o;
    o.x = (char)(int)rintf(v.x);
    o.y = (char)(int)rintf(v.y);
    o.z = (char)(int)rintf(v.z);
    o.w = (char)(int)rintf(v.w);
    dst[j] = o;
  }
}

// ----------------------------------------------------------------- GEMM -----
// out[m,n] = sum_k A[m,k]*B[n,k]  (both K-major int8), i32 accumulate (exact).
// BK=128, 128x128 tile, 32 MFMA per barrier, XOR-swizzled LDS (0 conflicts),
// coalesced glds width=16, XCD-aware block swizzle (R6: FETCH 805->328MB).
// R7: all epilogue stores NON-TEMPORAL + MODE1 ga_in loads non-temporal.
//
// R11: __launch_bounds__(256, 4) -- the ONLY change vs R7 (241us, 33.5%
// MfmaUtil).  Evidence across R7-R10: blocks/CU (TLP) dominates; the
// single-buffered stage->sync->compute->sync structure relies on co-resident
// blocks to cover its vmcnt(0) barrier drain (m114 implicit overlap).  At
// 64 VGPR + 64 AGPR = 128 unified regs/wave and 33KB LDS, FOUR 256-thread
// blocks/CU are legal (16 waves/CU, 4x33KB=132KB <= 160KB); R7 only asked
// for 3.  i8 uniquely affords this (bf16 needs 2x operand regs at same K).
//
// MODE 0: gate -> ga = silu(acc*gs), store f32, sum|ga| -> sums[0]
// MODE 1: up   -> inter = clip(rint(ga/ga_s))*acc*(ga_s*up_s), store f32,
//                 sum|inter| -> sums[1]
// MODE 2: down -> plain f32 store (exact integers)
template<int MODE>
__global__ __launch_bounds__(256, 4)
void gemm_i8(const char* __restrict__ A,
             const char* __restrict__ Bm,
             int M, int N, int K,
             float* __restrict__ Cout,
             const float* __restrict__ ga_in,
             const float* __restrict__ sc0,
             const float* __restrict__ sc1,
             double* __restrict__ sums,
             long long NN)
{
  __shared__ char As[16384];
  __shared__ char Bs[16384];
  __shared__ double red[4];

  const int tid  = threadIdx.x;
  const int w    = tid >> 6;        // wave 0..3
  const int lane = tid & 63;
  const int wr   = lane & 15;
  const int qd   = lane >> 4;
  const int wm   = (w >> 1) << 6;
  const int wn   = (w & 1) << 6;

  // XCD-aware swizzle (bijection over all (m_tile, n_tile))
  const int L   = blockIdx.y * gridDim.x + blockIdx.x;
  const int xcd = L & 7;
  const int r   = L >> 3;
  const int m0  = (xcd + ((r & 3) << 3)) << 7;
  const int n0  = (r >> 2) << 7;

  i32x4 acc[4][4] = {};

  // staging addresses
  const int rowL = tid >> 3;                    // 0..31
  const int chk  = (tid & 7) ^ (rowL & 7);
  const char* gA = A  + (size_t)(m0 + rowL) * K + (chk << 4);
  const char* gB = Bm + (size_t)(n0 + rowL) * K + (chk << 4);
  const size_t rk32 = (size_t)32 * K;
  char* lA = As + (w << 10);
  char* lB = Bs + (w << 10);

  // fragment LDS byte offsets (loop-invariant)
  const int s7    = wr & 7;
  const int abase = ((wm + wr) << 7) + ((qd ^ s7) << 4);
  const int bbase = ((wn + wr) << 7) + ((qd ^ s7) << 4);

  for (int k0 = 0; k0 < K; k0 += 128) {
    GLDS16(gA + k0,            lA);
    GLDS16(gA + k0 +     rk32, lA + 4096);
    GLDS16(gA + k0 + 2 * rk32, lA + 8192);
    GLDS16(gA + k0 + 3 * rk32, lA + 12288);
    GLDS16(gB + k0,            lB);
    GLDS16(gB + k0 +     rk32, lB + 4096);
    GLDS16(gB + k0 + 2 * rk32, lB + 8192);
    GLDS16(gB + k0 + 3 * rk32, lB + 12288);
    __syncthreads();

#pragma unroll
    for (int h = 0; h < 2; h++) {
      const int hx = h << 6;                    // toggles physical-chunk bit 2
      i32x4 af[4], bfr[4];
#pragma unroll
      for (int i = 0; i < 4; i++)
        af[i] = *(const i32x4*)(As + ((abase + (i << 11)) ^ hx));
#pragma unroll
      for (int j = 0; j < 4; j++)
        bfr[j] = *(const i32x4*)(Bs + ((bbase + (j << 11)) ^ hx));

#pragma unroll
      for (int i = 0; i < 4; i++)
#pragma unroll
        for (int j = 0; j < 4; j++)
          acc[i][j] = __builtin_amdgcn_mfma_i32_16x16x64_i8(af[i], bfr[j],
                                                            acc[i][j], 0, 0, 0);
    }
    __syncthreads();
  }

  // epilogue: C/D layout col = lane&15 (n), row = quad*4 + reg (m)
  double lsum = 0.0;

  if (MODE == 0) {
    const float gs = sc0[0] * sc1[0];
#pragma unroll
    for (int i = 0; i < 4; i++) {
      const int mb = m0 + wm + (i << 4) + (qd << 2);
#pragma unroll
      for (int j = 0; j < 4; j++) {
        const int n = n0 + wn + (j << 4) + wr;
#pragma unroll
        for (int r2 = 0; r2 < 4; r2++) {
          float g = (float)acc[i][j][r2] * gs;
          float s = g / (1.0f + expf(-g));          // silu
          __builtin_nontemporal_store(s, &Cout[(size_t)(mb + r2) * N + n]);
          lsum += (double)fabsf(s);
        }
      }
    }
  } else if (MODE == 1) {
    const float up_s  = sc0[0] * sc1[0];
    const float ga_s  = (float)(sums[0] / (double)NN) + 1e-8f;
    const float combo = ga_s * up_s;
#pragma unroll
    for (int i = 0; i < 4; i++) {
      const int mb = m0 + wm + (i << 4) + (qd << 2);
#pragma unroll
      for (int j = 0; j < 4; j++) {
        const int n = n0 + wn + (j << 4) + wr;
#pragma unroll
        for (int r2 = 0; r2 < 4; r2++) {
          float up = (float)acc[i][j][r2];
          float ga = __builtin_nontemporal_load(
                         &ga_in[(size_t)(mb + r2) * N + n]);
          float gq = fmaxf(-128.0f, fminf(127.0f, rintf(ga / ga_s)));
          float itv = gq * up * combo;              // same assoc as reference
          __builtin_nontemporal_store(itv, &Cout[(size_t)(mb + r2) * N + n]);
          lsum += (double)fabsf(itv);
        }
      }
    }
  } else {
#pragma unroll
    for (int i = 0; i < 4; i++) {
      const int mb = m0 + wm + (i << 4) + (qd << 2);
#pragma unroll
      for (int j = 0; j < 4; j++) {
        const int n = n0 + wn + (j << 4) + wr;
#pragma unroll
        for (int r2 = 0; r2 < 4; r2++)
          __builtin_nontemporal_store((float)acc[i][j][r2],
                                      &Cout[(size_t)(mb + r2) * N + n]);
      }
    }
  }

  if (MODE != 2) {
    for (int off = 32; off; off >>= 1) lsum += __shfl_down(lsum, off, 64);
    if (lane == 0) red[w] = lsum;
    __syncthreads();
    if (tid == 0) atomicAdd(&sums[MODE], red[0] + red[1] + red[2] + red[3]);
  }
}

// ------------------------------------------------------------- quantize -----
__global__ void quant_inter(const float* __restrict__ inter,
                            char* __restrict__ outq,
                            const double* __restrict__ sums, long long NN,
                            const float* __restrict__ wsd,
                            float* __restrict__ scalar_out, int n4)
{
  const float is = (float)(sums[1] / (double)NN) + 1e-8f;
  if (blockIdx.x == 0 && threadIdx.x == 0) scalar_out[0] = is * wsd[0];
  int stride = gridDim.x * blockDim.x;
  for (int i = blockIdx.x * blockDim.x + threadIdx.x; i < n4; i += stride) {
    f32x4v v = __builtin_nontemporal_load(&((const f32x4v*)inter)[i]);
    i8x4v o;
    o.x = (char)(int)fmaxf(-128.0f, fminf(127.0f, rintf(v.x / is)));
    o.y = (char)(int)fmaxf(-128.0f, fminf(127.0f, rintf(v.y / is)));
    o.z = (char)(int)fmaxf(-128.0f, fminf(127.0f, rintf(v.z / is)));
    o.w = (char)(int)fmaxf(-128.0f, fminf(127.0f, rintf(v.w / is)));
    ((i8x4v*)outq)[i] = o;                 // cacheable: GEMM2 reads it next
  }
}

// ---------------------------------------------------------------- launch ----
extern "C" void kernel_launch(void* const* d_in, const int* in_sizes, int n_in,
                              void* d_out, int out_size, void* d_ws, size_t ws_size,
                              hipStream_t stream) {
  const float* x        = (const float*)d_in[0];
  const float* x_scale  = (const float*)d_in[1];
  const float* qw_gate  = (const float*)d_in[2];
  const float* ws_gate  = (const float*)d_in[3];
  const float* qw_up    = (const float*)d_in[4];
  const float* ws_up    = (const float*)d_in[5];
  const float* qw_down  = (const float*)d_in[6];
  const float* ws_down  = (const float*)d_in[7];
  float* out = (float*)d_out;

  char* ws = (char*)d_ws;
  double* sums = (double*)ws;                 // [0]=sum|ga| [1]=sum|inter|
  size_t off = 256;
  char* xq     = ws + off; off += (size_t)TOK * HD;
  char* wgq    = ws + off; off += (size_t)ID * HD;
  char* wuq    = ws + off; off += (size_t)ID * HD;
  char* wdq    = ws + off; off += (size_t)HD * ID;
  char* interq = ws + off; off += (size_t)TOK * ID;
  float* ga    = (float*)(ws + off); off += (size_t)TOK * ID * 4;
  float* inter = (float*)(ws + off); off += (size_t)TOK * ID * 4;

  const long long NN = (long long)TOK * ID;

  (void)hipMemsetAsync(sums, 0, 16, stream);

  // all four converts in one launch
  conv_all<<<8192, 256, 0, stream>>>(x, xq, qw_gate, wgq, qw_up, wuq,
                                     qw_down, wdq);

  // gate GEMM + silu + sum|ga|
  gemm_i8<0><<<dim3(ID / 128, TOK / 128), 256, 0, stream>>>(
      xq, wgq, TOK, ID, HD, ga, nullptr, x_scale, ws_gate, sums, NN);

  // up GEMM + inter computation + sum|inter|
  gemm_i8<1><<<dim3(ID / 128, TOK / 128), 256, 0, stream>>>(
      xq, wuq, TOK, ID, HD, inter, ga, x_scale, ws_up, sums, NN);

  // quantize inter -> int8; also write scalar output
  quant_inter<<<8192, 256, 0, stream>>>(inter, interq, sums, NN, ws_down,
                                        out + (size_t)TOK * HD, (int)(NN / 4));

  // down GEMM -> final output (exact integers in f32)
  gemm_i8<2><<<dim3(HD / 128, TOK / 128), 256, 0, stream>>>(
      interq, wdq, TOK, HD, ID, out, nullptr, nullptr, nullptr, sums, NN);
}

// Round 5
// 1106.426 us; speedup vs baseline: 1.1100x; 1.0152x over previous
//
#include <hip/hip_runtime.h>
#include <math.h>

// Problem dims (fixed): B=2, S=2048 -> TOK=4096 tokens; H=4096; I=11008
#define TOK 4096
#define HD  4096
#define ID  11008

typedef int i32x4 __attribute__((ext_vector_type(4)));
typedef float f32x4v __attribute__((ext_vector_type(4)));  // ext-vector: OK for nontemporal builtins
typedef char i8x4v __attribute__((ext_vector_type(4)));

#define GLDS16(g, l) __builtin_amdgcn_global_load_lds( \
    (const __attribute__((address_space(1))) void*)(g), \
    (__attribute__((address_space(3))) void*)(l), 16, 0, 0)

// ---------------------------------------------------------------- convert ---
// All four f32 -> i8 converts fused into one launch. Reads are streamed-once
// (765MB) -> non-temporal so they don't thrash L3 ahead of the GEMMs; writes
// (191MB i8 total) stay cacheable -> L3-resident for the GEMMs that read them.
__global__ void conv_all(const float* __restrict__ x,  char* __restrict__ xq,
                         const float* __restrict__ wg, char* __restrict__ wgq,
                         const float* __restrict__ wu, char* __restrict__ wuq,
                         const float* __restrict__ wd, char* __restrict__ wdq)
{
  const long NX = (long)TOK * HD / 4, NW = (long)ID * HD / 4;
  const long total = NX + 3 * NW;
  const long stride = (long)gridDim.x * blockDim.x;
  for (long i = (long)blockIdx.x * blockDim.x + threadIdx.x; i < total;
       i += stride) {
    const f32x4v* src; i8x4v* dst; long j;
    if (i < NX)               { src = (const f32x4v*)x;  dst = (i8x4v*)xq;  j = i; }
    else if (i < NX + NW)     { src = (const f32x4v*)wg; dst = (i8x4v*)wgq; j = i - NX; }
    else if (i < NX + 2 * NW) { src = (const f32x4v*)wu; dst = (i8x4v*)wuq; j = i - NX - NW; }
    else                      { src = (const f32x4v*)wd; dst = (i8x4v*)wdq; j = i - NX - 2 * NW; }
    f32x4v v = __builtin_nontemporal_load(&src[j]);
    i8x4v o;
    o.x = (char)(int)rintf(v.x);
    o.y = (char)(int)rintf(v.y);
    o.z = (char)(int)rintf(v.z);
    o.w = (char)(int)rintf(v.w);
    dst[j] = o;
  }
}

// ----------------------------------------------------------------- GEMM -----
// out[m,n] = sum_k A[m,k]*B[n,k]  (both K-major int8), i32 accumulate (exact).
// BK=128, 128x128 tile, 32 MFMA per barrier, XOR-swizzled LDS (0 conflicts),
// coalesced glds width=16, XCD-aware block swizzle (R6: FETCH 805->328MB).
// R7: all epilogue stores NON-TEMPORAL + MODE1 ga_in loads non-temporal.
// R11: __launch_bounds__(256, 4) -- no effect: occupancy stayed 3 blocks/CU.
//
// R12: LDS 33280 -> exactly 32768 by deleting the separate red[4] array and
// reusing the first 32B of As for the cross-wave sum (safe: all LDS fragment
// reads complete before the K-loop's final __syncthreads; R10 used the same
// pattern).  Theory: the 32-byte red[] pushed LDS_Block_Size to 33280, and
// under any runtime LDS-allocation granule >512B that rounds up far enough
// that floor(160KB/granule(33280)) = 3 -- vetoing the 4th co-resident block
// that registers (128 x 16 = 2048) and wave slots otherwise permit.  32768
// is granule-aligned for every plausible granularity.
//
// MODE 0: gate -> ga = silu(acc*gs), store f32, sum|ga| -> sums[0]
// MODE 1: up   -> inter = clip(rint(ga/ga_s))*acc*(ga_s*up_s), store f32,
//                 sum|inter| -> sums[1]
// MODE 2: down -> plain f32 store (exact integers)
template<int MODE>
__global__ __launch_bounds__(256, 4)
void gemm_i8(const char* __restrict__ A,
             const char* __restrict__ Bm,
             int M, int N, int K,
             float* __restrict__ Cout,
             const float* __restrict__ ga_in,
             const float* __restrict__ sc0,
             const float* __restrict__ sc1,
             double* __restrict__ sums,
             long long NN)
{
  __shared__ char As[16384];
  __shared__ char Bs[16384];

  const int tid  = threadIdx.x;
  const int w    = tid >> 6;        // wave 0..3
  const int lane = tid & 63;
  const int wr   = lane & 15;
  const int qd   = lane >> 4;
  const int wm   = (w >> 1) << 6;
  const int wn   = (w & 1) << 6;

  // XCD-aware swizzle (bijection over all (m_tile, n_tile))
  const int L   = blockIdx.y * gridDim.x + blockIdx.x;
  const int xcd = L & 7;
  const int r   = L >> 3;
  const int m0  = (xcd + ((r & 3) << 3)) << 7;
  const int n0  = (r >> 2) << 7;

  i32x4 acc[4][4] = {};

  // staging addresses
  const int rowL = tid >> 3;                    // 0..31
  const int chk  = (tid & 7) ^ (rowL & 7);
  const char* gA = A  + (size_t)(m0 + rowL) * K + (chk << 4);
  const char* gB = Bm + (size_t)(n0 + rowL) * K + (chk << 4);
  const size_t rk32 = (size_t)32 * K;
  char* lA = As + (w << 10);
  char* lB = Bs + (w << 10);

  // fragment LDS byte offsets (loop-invariant)
  const int s7    = wr & 7;
  const int abase = ((wm + wr) << 7) + ((qd ^ s7) << 4);
  const int bbase = ((wn + wr) << 7) + ((qd ^ s7) << 4);

  for (int k0 = 0; k0 < K; k0 += 128) {
    GLDS16(gA + k0,            lA);
    GLDS16(gA + k0 +     rk32, lA + 4096);
    GLDS16(gA + k0 + 2 * rk32, lA + 8192);
    GLDS16(gA + k0 + 3 * rk32, lA + 12288);
    GLDS16(gB + k0,            lB);
    GLDS16(gB + k0 +     rk32, lB + 4096);
    GLDS16(gB + k0 + 2 * rk32, lB + 8192);
    GLDS16(gB + k0 + 3 * rk32, lB + 12288);
    __syncthreads();

#pragma unroll
    for (int h = 0; h < 2; h++) {
      const int hx = h << 6;                    // toggles physical-chunk bit 2
      i32x4 af[4], bfr[4];
#pragma unroll
      for (int i = 0; i < 4; i++)
        af[i] = *(const i32x4*)(As + ((abase + (i << 11)) ^ hx));
#pragma unroll
      for (int j = 0; j < 4; j++)
        bfr[j] = *(const i32x4*)(Bs + ((bbase + (j << 11)) ^ hx));

#pragma unroll
      for (int i = 0; i < 4; i++)
#pragma unroll
        for (int j = 0; j < 4; j++)
          acc[i][j] = __builtin_amdgcn_mfma_i32_16x16x64_i8(af[i], bfr[j],
                                                            acc[i][j], 0, 0, 0);
    }
    __syncthreads();
  }

  // epilogue: C/D layout col = lane&15 (n), row = quad*4 + reg (m)
  double lsum = 0.0;

  if (MODE == 0) {
    const float gs = sc0[0] * sc1[0];
#pragma unroll
    for (int i = 0; i < 4; i++) {
      const int mb = m0 + wm + (i << 4) + (qd << 2);
#pragma unroll
      for (int j = 0; j < 4; j++) {
        const int n = n0 + wn + (j << 4) + wr;
#pragma unroll
        for (int r2 = 0; r2 < 4; r2++) {
          float g = (float)acc[i][j][r2] * gs;
          float s = g / (1.0f + expf(-g));          // silu
          __builtin_nontemporal_store(s, &Cout[(size_t)(mb + r2) * N + n]);
          lsum += (double)fabsf(s);
        }
      }
    }
  } else if (MODE == 1) {
    const float up_s  = sc0[0] * sc1[0];
    const float ga_s  = (float)(sums[0] / (double)NN) + 1e-8f;
    const float combo = ga_s * up_s;
#pragma unroll
    for (int i = 0; i < 4; i++) {
      const int mb = m0 + wm + (i << 4) + (qd << 2);
#pragma unroll
      for (int j = 0; j < 4; j++) {
        const int n = n0 + wn + (j << 4) + wr;
#pragma unroll
        for (int r2 = 0; r2 < 4; r2++) {
          float up = (float)acc[i][j][r2];
          float ga = __builtin_nontemporal_load(
                         &ga_in[(size_t)(mb + r2) * N + n]);
          float gq = fmaxf(-128.0f, fminf(127.0f, rintf(ga / ga_s)));
          float itv = gq * up * combo;              // same assoc as reference
          __builtin_nontemporal_store(itv, &Cout[(size_t)(mb + r2) * N + n]);
          lsum += (double)fabsf(itv);
        }
      }
    }
  } else {
#pragma unroll
    for (int i = 0; i < 4; i++) {
      const int mb = m0 + wm + (i << 4) + (qd << 2);
#pragma unroll
      for (int j = 0; j < 4; j++) {
        const int n = n0 + wn + (j << 4) + wr;
#pragma unroll
        for (int r2 = 0; r2 < 4; r2++)
          __builtin_nontemporal_store((float)acc[i][j][r2],
                                      &Cout[(size_t)(mb + r2) * N + n]);
      }
    }
  }

  if (MODE != 2) {
    for (int off = 32; off; off >>= 1) lsum += __shfl_down(lsum, off, 64);
    double* red = (double*)As;   // reuse LDS: all fragment reads are done
    if (lane == 0) red[w] = lsum;
    __syncthreads();
    if (tid == 0) atomicAdd(&sums[MODE], red[0] + red[1] + red[2] + red[3]);
  }
}

// ------------------------------------------------------------- quantize -----
__global__ void quant_inter(const float* __restrict__ inter,
                            char* __restrict__ outq,
                            const double* __restrict__ sums, long long NN,
                            const float* __restrict__ wsd,
                            float* __restrict__ scalar_out, int n4)
{
  const float is = (float)(sums[1] / (double)NN) + 1e-8f;
  if (blockIdx.x == 0 && threadIdx.x == 0) scalar_out[0] = is * wsd[0];
  int stride = gridDim.x * blockDim.x;
  for (int i = blockIdx.x * blockDim.x + threadIdx.x; i < n4; i += stride) {
    f32x4v v = __builtin_nontemporal_load(&((const f32x4v*)inter)[i]);
    i8x4v o;
    o.x = (char)(int)fmaxf(-128.0f, fminf(127.0f, rintf(v.x / is)));
    o.y = (char)(int)fmaxf(-128.0f, fminf(127.0f, rintf(v.y / is)));
    o.z = (char)(int)fmaxf(-128.0f, fminf(127.0f, rintf(v.z / is)));
    o.w = (char)(int)fmaxf(-128.0f, fminf(127.0f, rintf(v.w / is)));
    ((i8x4v*)outq)[i] = o;                 // cacheable: GEMM2 reads it next
  }
}

// ---------------------------------------------------------------- launch ----
extern "C" void kernel_launch(void* const* d_in, const int* in_sizes, int n_in,
                              void* d_out, int out_size, void* d_ws, size_t ws_size,
                              hipStream_t stream) {
  const float* x        = (const float*)d_in[0];
  const float* x_scale  = (const float*)d_in[1];
  const float* qw_gate  = (const float*)d_in[2];
  const float* ws_gate  = (const float*)d_in[3];
  const float* qw_up    = (const float*)d_in[4];
  const float* ws_up    = (const float*)d_in[5];
  const float* qw_down  = (const float*)d_in[6];
  const float* ws_down  = (const float*)d_in[7];
  float* out = (float*)d_out;

  char* ws = (char*)d_ws;
  double* sums = (double*)ws;                 // [0]=sum|ga| [1]=sum|inter|
  size_t off = 256;
  char* xq     = ws + off; off += (size_t)TOK * HD;
  char* wgq    = ws + off; off += (size_t)ID * HD;
  char* wuq    = ws + off; off += (size_t)ID * HD;
  char* wdq    = ws + off; off += (size_t)HD * ID;
  char* interq = ws + off; off += (size_t)TOK * ID;
  float* ga    = (float*)(ws + off); off += (size_t)TOK * ID * 4;
  float* inter = (float*)(ws + off); off += (size_t)TOK * ID * 4;

  const long long NN = (long long)TOK * ID;

  (void)hipMemsetAsync(sums, 0, 16, stream);

  // all four converts in one launch
  conv_all<<<8192, 256, 0, stream>>>(x, xq, qw_gate, wgq, qw_up, wuq,
                                     qw_down, wdq);

  // gate GEMM + silu + sum|ga|
  gemm_i8<0><<<dim3(ID / 128, TOK / 128), 256, 0, stream>>>(
      xq, wgq, TOK, ID, HD, ga, nullptr, x_scale, ws_gate, sums, NN);

  // up GEMM + inter computation + sum|inter|
  gemm_i8<1><<<dim3(ID / 128, TOK / 128), 256, 0, stream>>>(
      xq, wuq, TOK, ID, HD, inter, ga, x_scale, ws_up, sums, NN);

  // quantize inter -> int8; also write scalar output
  quant_inter<<<8192, 256, 0, stream>>>(inter, interq, sums, NN, ws_down,
                                        out + (size_t)TOK * HD, (int)(NN / 4));

  // down GEMM -> final output (exact integers in f32)
  gemm_i8<2><<<dim3(HD / 128, TOK / 128), 256, 0, stream>>>(
      interq, wdq, TOK, HD, ID, out, nullptr, nullptr, nullptr, sums, NN);
}